// Round 5
// baseline (366.169 us; speedup 1.0000x reference)
//
#include <hip/hip_runtime.h>

#define NN 50000
#define NE 600000
#define DD 128
#define NPAD 50048      // 782 * 64
#define NTILE 782       // NPAD / 64
#define SETUP_BLOCKS 12501   // ceil((NN+1) waves / 4 waves-per-block)
#define E4_BLOCKS 586        // ceil(NE/4 / 256)
#define SCAN_BLOCKS 49       // ceil(NN / 1024)

typedef __attribute__((ext_vector_type(8))) short bf16x8;
typedef __attribute__((ext_vector_type(4))) float f32x4;

__device__ __forceinline__ float bf2f(unsigned int u16) {
    union { unsigned int i; float f; } v; v.i = u16 << 16; return v.f;
}
__device__ __forceinline__ unsigned short f2bf(float f) {
    union { float f; unsigned int i; } v; v.f = f;
    unsigned int i = v.i + 0x7FFFu + ((v.i >> 16) & 1u);
    return (unsigned short)(i >> 16);
}
__device__ __forceinline__ float wred64(float v) {
    #pragma unroll
    for (int o = 32; o; o >>= 1) v += __shfl_xor(v, o, 64);
    return v;
}
__device__ __forceinline__ int tame16(unsigned int u) {
    int e = (int)((u >> 7) & 0xFF);
    return (e >= 100 && e <= 133) ? 1 : 0;
}

// ---- per-block inline flag probes (L2-broadcast reads) ----

__device__ __forceinline__ int probe_e64(const int* __restrict__ ei, int t,
                                         int* f_s) {
    if (t < 64) {
        int nz = 0;
        #pragma unroll
        for (int i = 0; i < 4; ++i) nz |= ei[2 * (t * 4 + i) + 1];
        #pragma unroll
        for (int o = 32; o; o >>= 1) nz |= __shfl_xor(nz, o, 64);
        if (t == 0) *f_s = (nz == 0) ? 1 : 0;
    }
    __syncthreads();
    return *f_s;
}

__device__ __forceinline__ int probe_bf16(const unsigned int* __restrict__ p,
                                          int t, int* f_s) {
    if (t < 64) {
        int tc = tame16(p[t] & 0xFFFFu);
        #pragma unroll
        for (int o = 32; o; o >>= 1) tc += __shfl_xor(tc, o, 64);
        if (t == 0) *f_s = (tc >= 48) ? 1 : 0;
    }
    __syncthreads();
    return *f_s;
}

// ---------------- kernels (6 dispatches) ----------------

// D1: probe + W/b convert + zero(deg,pf) + prep featu (row NN = zero row)
__global__ __launch_bounds__(256) void setup_k(
    const void* __restrict__ x,
    const void* __restrict__ W1, const void* __restrict__ b1,
    const void* __restrict__ W2, const void* __restrict__ b2,
    unsigned short* __restrict__ W1b, unsigned short* __restrict__ b1b,
    unsigned short* __restrict__ W2b, unsigned short* __restrict__ b2b,
    int* __restrict__ deg, int* __restrict__ pf,
    unsigned int* __restrict__ featu) {
    __shared__ int fx_s, fw_s;
    const int t = threadIdx.x;
    if (t < 64) {
        int tx = tame16(((const unsigned int*)x)[t] & 0xFFFFu);
        int tw = tame16(((const unsigned int*)W1)[t] & 0xFFFFu);
        #pragma unroll
        for (int o = 32; o; o >>= 1) {
            tx += __shfl_xor(tx, o, 64);
            tw += __shfl_xor(tw, o, 64);
        }
        if (t == 0) { fx_s = (tx >= 48) ? 1 : 0; fw_s = (tw >= 48) ? 1 : 0; }
    }
    __syncthreads();
    const int f_xb = fx_s, f_wb = fw_s;
    const int b = blockIdx.x;
    const int tid = b * 256 + t;
    const int nthr = gridDim.x * 256;

    for (int i = tid; i < DD * DD; i += nthr) {
        if (f_wb) {
            W1b[i] = ((const unsigned short*)W1)[i];
            W2b[i] = ((const unsigned short*)W2)[i];
            if (i < DD) { b1b[i] = ((const unsigned short*)b1)[i];
                          b2b[i] = ((const unsigned short*)b2)[i]; }
        } else {
            W1b[i] = f2bf(((const float*)W1)[i]);
            W2b[i] = f2bf(((const float*)W2)[i]);
            if (i < DD) { b1b[i] = f2bf(((const float*)b1)[i]);
                          b2b[i] = f2bf(((const float*)b2)[i]); }
        }
    }
    for (int i = tid; i < NN + 64; i += nthr) {
        if (i < NN) deg[i] = 0; else pf[i - NN] = 0;
    }
    const int lane = t & 63;
    const int wv = t >> 6;
    const int nwv = gridDim.x * 4;
    for (int row = b * 4 + wv; row <= NN; row += nwv) {
        if (row == NN) { featu[(size_t)NN * 64 + lane] = 0u; continue; }
        float v0, v1;
        if (f_xb) {
            const unsigned int px = ((const unsigned int*)x)[(size_t)row * 64 + lane];
            v0 = bf2f(px & 0xFFFFu); v1 = bf2f(px >> 16);
        } else {
            const float2 px = ((const float2*)x)[(size_t)row * 64 + lane];
            v0 = px.x; v1 = px.y;
        }
        const float ss = wred64(v0 * v0 + v1 * v1);
        const float nrm = sqrtf(ss);
        const float sc = nrm > 1.0f ? 1.0f / nrm : 1.0f;
        featu[(size_t)row * 64 + lane] =
            (unsigned int)f2bf(v0 * sc) | ((unsigned int)f2bf(v1 * sc) << 16);
    }
}

// D2: in-degree histogram, 4 edges/thread (4 independent atomics in flight)
__global__ __launch_bounds__(256) void hist_k(
    const int* __restrict__ ei, int* __restrict__ deg) {
    __shared__ int f_s;
    const int f_e64 = probe_e64(ei, threadIdx.x, &f_s);
    const int e0 = (blockIdx.x * 256 + threadIdx.x) * 4;
    if (e0 >= NE) return;
    int d[4];
    #pragma unroll
    for (int q = 0; q < 4; ++q) {
        const int e = e0 + q;
        d[q] = (e < NE)
            ? (f_e64 ? (int)((const long long*)ei)[NE + e] : ei[NE + e])
            : -1;
    }
    #pragma unroll
    for (int q = 0; q < 4; ++q)
        if (d[q] >= 0) atomicAdd(&deg[d[q]], 1);
}

// D3: single-dispatch exclusive scan (verified round-3 body)
__global__ __launch_bounds__(1024) void scan_k(
    const int* __restrict__ deg, int* __restrict__ offs,
    int* __restrict__ cursor, int* __restrict__ pf) {
    __shared__ int wsum[16];
    __shared__ int wbase[16];
    __shared__ int base_s;
    const int tid = threadIdx.x, lane = tid & 63, wv = tid >> 6;
    const int b = blockIdx.x;
    const int i = b * 1024 + tid;
    const int v = (i < NN) ? deg[i] : 0;
    int incl = v;
    #pragma unroll
    for (int off = 1; off < 64; off <<= 1) {
        int t = __shfl_up(incl, off, 64);
        if (lane >= off) incl += t;
    }
    if (lane == 63) wsum[wv] = incl;
    __syncthreads();
    if (wv == 0 && lane < 16) {
        const int wv_v = wsum[lane];
        int wincl = wv_v;
        #pragma unroll
        for (int off = 1; off < 16; off <<= 1) {
            int t = __shfl_up(wincl, off, 64);
            if (lane >= off) wincl += t;
        }
        wbase[lane] = wincl - wv_v;
        if (lane == 15)
            __hip_atomic_store(&pf[b], wincl + 1, __ATOMIC_RELEASE,
                               __HIP_MEMORY_SCOPE_AGENT);
    }
    if (wv == 0) {
        int val = 0;
        while (true) {
            if (lane < SCAN_BLOCKS && val == 0)
                val = __hip_atomic_load(&pf[lane], __ATOMIC_ACQUIRE,
                                        __HIP_MEMORY_SCOPE_AGENT);
            if (__ballot(lane < SCAN_BLOCKS && val == 0) == 0ull) break;
            __builtin_amdgcn_s_sleep(1);
        }
        int pv = (lane < SCAN_BLOCKS) ? val - 1 : 0;
        int ex = pv;
        #pragma unroll
        for (int off = 1; off < 64; off <<= 1) {
            int t = __shfl_up(ex, off, 64);
            if (lane >= off) ex += t;
        }
        ex -= pv;
        if (lane == b) base_s = ex;
    }
    __syncthreads();
    if (i < NN) {
        const int o = base_s + wbase[wv] + incl - v;
        offs[i] = o;
        cursor[i] = o;
    }
    if (b == 0 && tid == 0) offs[NN] = NE;
}

// D4: fill CSR adjacency, 4 edges/thread
__global__ __launch_bounds__(256) void fill_k(
    const int* __restrict__ ei, int* __restrict__ cursor,
    int* __restrict__ eidx) {
    __shared__ int f_s;
    const int f_e64 = probe_e64(ei, threadIdx.x, &f_s);
    const int e0 = (blockIdx.x * 256 + threadIdx.x) * 4;
    if (e0 >= NE) return;
    int s[4], d[4];
    #pragma unroll
    for (int q = 0; q < 4; ++q) {
        const int e = e0 + q;
        if (e < NE) {
            if (f_e64) {
                const long long* e64 = (const long long*)ei;
                s[q] = (int)e64[e]; d[q] = (int)e64[NE + e];
            } else {
                s[q] = ei[e]; d[q] = ei[NE + e];
            }
        } else d[q] = -1;
    }
    int pos[4];
    #pragma unroll
    for (int q = 0; q < 4; ++q)
        if (d[q] >= 0) pos[q] = atomicAdd(&cursor[d[q]], 1);
    #pragma unroll
    for (int q = 0; q < 4; ++q)
        if (d[q] >= 0) eidx[pos[q]] = s[q];
}

// D5/D6: fused aggregate + MFMA GEMM per 64-row tile.
// Each wave aggregates exactly the 16 rows its MFMA A-fragments read (no
// cross-wave LDS dependency). uint4 gather: 16 lanes x 16B = one 256B row,
// 4 rows per load instruction via lane groups h=0..3.
template<bool LAYER1>
__global__ __launch_bounds__(256) void aggemm_k(
    const int* __restrict__ offs, const int* __restrict__ eidx,
    const uint4* __restrict__ featu4, const void* __restrict__ noise,
    const unsigned int* __restrict__ nprobe,
    const unsigned short* __restrict__ Wb, const unsigned short* __restrict__ bb,
    unsigned short* __restrict__ featb,     // LAYER1 out (bf16, NPAD rows)
    float* __restrict__ outf) {             // LAYER2 out (f32, NN rows)
    __shared__ unsigned short Wl[128 * 136];
    __shared__ unsigned short bl[128];
    __shared__ unsigned short As[64 * 136];
    __shared__ int f_s;
    const int t = threadIdx.x;
    const int f_nb = probe_bf16(nprobe, t, &f_s);

    // stage W/b (global loads issue early, hide under gather)
    #pragma unroll
    for (int i = 0; i < 8; ++i) {
        const int idx8 = t + i * 256;
        const int base = idx8 * 8;
        *(uint4*)&Wl[(base >> 7) * 136 + (base & 127)] = ((const uint4*)Wb)[idx8];
    }
    if (t < 128) bl[t] = bb[t];

    const int lane = t & 63;
    const int w = t >> 6;
    const int c = lane & 15;   // 16B column group (cols 8c..8c+7)
    const int h = lane >> 4;   // row group 0..3
    const int rbase = blockIdx.x * 64 + w * 16;

    // aggregate this wave's 16 rows into As
    for (int i = 0; i < 16; ++i) {
        const int node = rbase + i;
        float a0 = 0.f, a1 = 0.f, a2 = 0.f, a3 = 0.f;
        float a4 = 0.f, a5 = 0.f, a6 = 0.f, a7 = 0.f;
        if (node < NN) {
            // self + noise terms split across h groups (independent loads)
            if (h == 0) {
                const uint4 sv = featu4[(size_t)node * 16 + c];
                a0 += bf2f(sv.x & 0xFFFFu); a1 += bf2f(sv.x >> 16);
                a2 += bf2f(sv.y & 0xFFFFu); a3 += bf2f(sv.y >> 16);
                a4 += bf2f(sv.z & 0xFFFFu); a5 += bf2f(sv.z >> 16);
                a6 += bf2f(sv.w & 0xFFFFu); a7 += bf2f(sv.w >> 16);
            } else if (h == 1) {
                if (f_nb) {
                    const uint4 nv = ((const uint4*)noise)[(size_t)node * 16 + c];
                    a0 += bf2f(nv.x & 0xFFFFu); a1 += bf2f(nv.x >> 16);
                    a2 += bf2f(nv.y & 0xFFFFu); a3 += bf2f(nv.y >> 16);
                    a4 += bf2f(nv.z & 0xFFFFu); a5 += bf2f(nv.z >> 16);
                    a6 += bf2f(nv.w & 0xFFFFu); a7 += bf2f(nv.w >> 16);
                }
            } else if (h == 2) {
                if (!f_nb) {
                    const float4 nv = ((const float4*)noise)[(size_t)node * 32 + 2 * c];
                    a0 += nv.x; a1 += nv.y; a2 += nv.z; a3 += nv.w;
                }
            } else {
                if (!f_nb) {
                    const float4 nv = ((const float4*)noise)[(size_t)node * 32 + 2 * c + 1];
                    a4 += nv.x; a5 += nv.y; a6 += nv.z; a7 += nv.w;
                }
            }
            const int e0 = offs[node];
            const int cnt = offs[node + 1] - e0;
            for (int base = 0; base < cnt; base += 64) {
                const int rem = cnt - base;
                int myi = NN;
                if (lane < rem) myi = eidx[e0 + base + lane];
                const int ecap = rem < 64 ? rem : 64;
                const int qb = (ecap + 15) & ~15;   // edges rounded to 16
                for (int p = 0; p < qb; p += 16) {
                    uint4 u[4];
                    #pragma unroll
                    for (int q = 0; q < 4; ++q) {
                        const int s = __shfl(myi, p + 4 * q + h, 64);
                        u[q] = featu4[(size_t)s * 16 + c];
                    }
                    #pragma unroll
                    for (int q = 0; q < 4; ++q) {
                        a0 += bf2f(u[q].x & 0xFFFFu); a1 += bf2f(u[q].x >> 16);
                        a2 += bf2f(u[q].y & 0xFFFFu); a3 += bf2f(u[q].y >> 16);
                        a4 += bf2f(u[q].z & 0xFFFFu); a5 += bf2f(u[q].z >> 16);
                        a6 += bf2f(u[q].w & 0xFFFFu); a7 += bf2f(u[q].w >> 16);
                    }
                }
            }
        }
        // sum the 4 row groups (every lane ends with the full row sum)
        a0 += __shfl_xor(a0, 16, 64); a0 += __shfl_xor(a0, 32, 64);
        a1 += __shfl_xor(a1, 16, 64); a1 += __shfl_xor(a1, 32, 64);
        a2 += __shfl_xor(a2, 16, 64); a2 += __shfl_xor(a2, 32, 64);
        a3 += __shfl_xor(a3, 16, 64); a3 += __shfl_xor(a3, 32, 64);
        a4 += __shfl_xor(a4, 16, 64); a4 += __shfl_xor(a4, 32, 64);
        a5 += __shfl_xor(a5, 16, 64); a5 += __shfl_xor(a5, 32, 64);
        a6 += __shfl_xor(a6, 16, 64); a6 += __shfl_xor(a6, 32, 64);
        a7 += __shfl_xor(a7, 16, 64); a7 += __shfl_xor(a7, 32, 64);
        if (h == 0) {
            uint4 o;
            o.x = (unsigned int)f2bf(a0) | ((unsigned int)f2bf(a1) << 16);
            o.y = (unsigned int)f2bf(a2) | ((unsigned int)f2bf(a3) << 16);
            o.z = (unsigned int)f2bf(a4) | ((unsigned int)f2bf(a5) << 16);
            o.w = (unsigned int)f2bf(a6) | ((unsigned int)f2bf(a7) << 16);
            *(uint4*)&As[(w * 16 + i) * 136 + c * 8] = o;
        }
    }

    __syncthreads();   // Wl/bl ready (As is same-wave only)

    const int n15 = c;
    const int quad = h;
    bf16x8 af[4];
    #pragma unroll
    for (int kc = 0; kc < 4; ++kc)
        af[kc] = *(const bf16x8*)&As[(w * 16 + n15) * 136 + kc * 32 + quad * 8];

    float hh[32];
    #pragma unroll
    for (int nt = 0; nt < 8; ++nt) {
        f32x4 acc = {0.f, 0.f, 0.f, 0.f};
        #pragma unroll
        for (int kc = 0; kc < 4; ++kc) {
            const bf16x8 bfr =
                *(const bf16x8*)&Wl[(nt * 16 + n15) * 136 + kc * 32 + quad * 8];
            acc = __builtin_amdgcn_mfma_f32_16x16x32_bf16(af[kc], bfr, acc, 0, 0, 0);
        }
        const float bj = bf2f((unsigned int)bl[nt * 16 + n15]);
        #pragma unroll
        for (int r = 0; r < 4; ++r) hh[nt * 4 + r] = acc[r] + bj;
    }

    if (LAYER1) {
        const float S = 1.0507009873554805f, AL = 1.6732632423543772f;
        float ss[4] = {0.f, 0.f, 0.f, 0.f};
        #pragma unroll
        for (int nt = 0; nt < 8; ++nt)
            #pragma unroll
            for (int r = 0; r < 4; ++r) {
                float v = hh[nt * 4 + r];
                v = v > 0.f ? S * v : S * AL * expm1f(v);
                hh[nt * 4 + r] = v;
                ss[r] += v * v;
            }
        #pragma unroll
        for (int r = 0; r < 4; ++r) {
            #pragma unroll
            for (int off = 1; off < 16; off <<= 1)
                ss[r] += __shfl_xor(ss[r], off, 64);
        }
        #pragma unroll
        for (int r = 0; r < 4; ++r) {
            const float nr = sqrtf(ss[r]);
            const float sc = nr > 1.f ? 1.f / nr : 1.f;
            const int row = rbase + quad * 4 + r;
            if (row < NN) {
                #pragma unroll
                for (int nt = 0; nt < 8; ++nt)
                    featb[(size_t)row * DD + nt * 16 + n15] =
                        f2bf(hh[nt * 4 + r] * sc);
            } else {
                // zero-pad rows NN..NPAD-1 (row NN is layer-2 gather target)
                #pragma unroll
                for (int nt = 0; nt < 8; ++nt)
                    featb[(size_t)row * DD + nt * 16 + n15] = 0;
            }
        }
    } else {
        #pragma unroll
        for (int r = 0; r < 4; ++r) {
            const int row = rbase + quad * 4 + r;
            if (row < NN) {
                #pragma unroll
                for (int nt = 0; nt < 8; ++nt)
                    outf[(size_t)row * DD + nt * 16 + n15] = hh[nt * 4 + r];
            }
        }
    }
}

extern "C" void kernel_launch(void* const* d_in, const int* in_sizes, int n_in,
                              void* d_out, int out_size, void* d_ws, size_t ws_size,
                              hipStream_t stream) {
    const void* x  = d_in[0];
    const int*  ei = (const int*)d_in[1];
    const void* W1 = d_in[2];
    const void* b1 = d_in[3];
    const void* W2 = d_in[4];
    const void* b2 = d_in[5];
    const void* n1 = d_in[6];
    const void* n2 = d_in[7];

    // ws layout (~16 MB)
    unsigned short* hbuf = (unsigned short*)d_ws;        // NPAD*128 bf16 (layer-2 features)
    unsigned short* W1b  = hbuf + (size_t)NPAD * DD;
    unsigned short* b1b  = W1b + DD * DD;
    unsigned short* W2b  = b1b + DD;
    unsigned short* b2b  = W2b + DD * DD;
    int* deg    = (int*)(b2b + DD);
    int* offs   = deg + NN;
    int* cursor = offs + NN + 1;
    int* pf     = cursor + NN;
    int* eidx   = pf + 64;
    unsigned int* featu = (unsigned int*)d_out;          // layer-1 features (NN+1 rows)

    // D1: probe + convert + zero + prep
    setup_k<<<SETUP_BLOCKS, 256, 0, stream>>>(
        x, W1, b1, W2, b2, W1b, b1b, W2b, b2b, deg, pf, featu);
    // D2-D4: CSR build
    hist_k<<<E4_BLOCKS, 256, 0, stream>>>(ei, deg);
    scan_k<<<SCAN_BLOCKS, 1024, 0, stream>>>(deg, offs, cursor, pf);
    fill_k<<<E4_BLOCKS, 256, 0, stream>>>(ei, cursor, eidx);
    // D5: layer 1 fused agg+gemm (reads featu/d_out, writes hbuf/ws)
    aggemm_k<true><<<NTILE, 256, 0, stream>>>(
        offs, eidx, (const uint4*)featu, n1, (const unsigned int*)n1,
        W1b, b1b, hbuf, nullptr);
    // D6: layer 2 fused agg+gemm (reads hbuf/ws, writes d_out f32)
    aggemm_k<false><<<NTILE, 256, 0, stream>>>(
        offs, eidx, (const uint4*)hbuf, n2, (const unsigned int*)n1,
        W2b, b2b, nullptr, (float*)d_out);
}

// Round 6
// 280.362 us; speedup vs baseline: 1.3061x; 1.3061x over previous
//
#include <hip/hip_runtime.h>

#define NN 50000
#define NE 600000
#define DD 128
#define NPAD 50048      // 782 * 64
#define NTILE 782       // NPAD / 64
#define SETUP_BLOCKS 12501   // ceil((NN+1) waves / 4 waves-per-block)
#define E4_BLOCKS 586        // ceil(NE/4 / 256)
#define SCAN_BLOCKS 49       // ceil(NN / 1024)

typedef __attribute__((ext_vector_type(8))) short bf16x8;
typedef __attribute__((ext_vector_type(4))) float f32x4;

__device__ __forceinline__ float bf2f(unsigned int u16) {
    union { unsigned int i; float f; } v; v.i = u16 << 16; return v.f;
}
__device__ __forceinline__ unsigned short f2bf(float f) {
    union { float f; unsigned int i; } v; v.f = f;
    unsigned int i = v.i + 0x7FFFu + ((v.i >> 16) & 1u);
    return (unsigned short)(i >> 16);
}
__device__ __forceinline__ float wred64(float v) {
    #pragma unroll
    for (int o = 32; o; o >>= 1) v += __shfl_xor(v, o, 64);
    return v;
}
__device__ __forceinline__ int tame16(unsigned int u) {
    int e = (int)((u >> 7) & 0xFF);
    return (e >= 100 && e <= 133) ? 1 : 0;
}

// ---- per-block inline flag probes (L2-broadcast reads) ----

__device__ __forceinline__ int probe_e64(const int* __restrict__ ei, int t,
                                         int* f_s) {
    if (t < 64) {
        int nz = 0;
        #pragma unroll
        for (int i = 0; i < 4; ++i) nz |= ei[2 * (t * 4 + i) + 1];
        #pragma unroll
        for (int o = 32; o; o >>= 1) nz |= __shfl_xor(nz, o, 64);
        if (t == 0) *f_s = (nz == 0) ? 1 : 0;
    }
    __syncthreads();
    return *f_s;
}

__device__ __forceinline__ int probe_bf16(const unsigned int* __restrict__ p,
                                          int t, int* f_s) {
    if (t < 64) {
        int tc = tame16(p[t] & 0xFFFFu);
        #pragma unroll
        for (int o = 32; o; o >>= 1) tc += __shfl_xor(tc, o, 64);
        if (t == 0) *f_s = (tc >= 48) ? 1 : 0;
    }
    __syncthreads();
    return *f_s;
}

// ---------------- kernels (8 dispatches) ----------------

// D1: probe + W/b convert + zero(deg,pf) + prep featu (row NN = zero row)
__global__ __launch_bounds__(256) void setup_k(
    const void* __restrict__ x,
    const void* __restrict__ W1, const void* __restrict__ b1,
    const void* __restrict__ W2, const void* __restrict__ b2,
    unsigned short* __restrict__ W1b, unsigned short* __restrict__ b1b,
    unsigned short* __restrict__ W2b, unsigned short* __restrict__ b2b,
    int* __restrict__ deg, int* __restrict__ pf,
    unsigned int* __restrict__ featu) {
    __shared__ int fx_s, fw_s;
    const int t = threadIdx.x;
    if (t < 64) {
        int tx = tame16(((const unsigned int*)x)[t] & 0xFFFFu);
        int tw = tame16(((const unsigned int*)W1)[t] & 0xFFFFu);
        #pragma unroll
        for (int o = 32; o; o >>= 1) {
            tx += __shfl_xor(tx, o, 64);
            tw += __shfl_xor(tw, o, 64);
        }
        if (t == 0) { fx_s = (tx >= 48) ? 1 : 0; fw_s = (tw >= 48) ? 1 : 0; }
    }
    __syncthreads();
    const int f_xb = fx_s, f_wb = fw_s;
    const int b = blockIdx.x;
    const int tid = b * 256 + t;
    const int nthr = gridDim.x * 256;

    for (int i = tid; i < DD * DD; i += nthr) {
        if (f_wb) {
            W1b[i] = ((const unsigned short*)W1)[i];
            W2b[i] = ((const unsigned short*)W2)[i];
            if (i < DD) { b1b[i] = ((const unsigned short*)b1)[i];
                          b2b[i] = ((const unsigned short*)b2)[i]; }
        } else {
            W1b[i] = f2bf(((const float*)W1)[i]);
            W2b[i] = f2bf(((const float*)W2)[i]);
            if (i < DD) { b1b[i] = f2bf(((const float*)b1)[i]);
                          b2b[i] = f2bf(((const float*)b2)[i]); }
        }
    }
    for (int i = tid; i < NN + 64; i += nthr) {
        if (i < NN) deg[i] = 0; else pf[i - NN] = 0;
    }
    const int lane = t & 63;
    const int wv = t >> 6;
    const int nwv = gridDim.x * 4;
    for (int row = b * 4 + wv; row <= NN; row += nwv) {
        if (row == NN) { featu[(size_t)NN * 64 + lane] = 0u; continue; }
        float v0, v1;
        if (f_xb) {
            const unsigned int px = ((const unsigned int*)x)[(size_t)row * 64 + lane];
            v0 = bf2f(px & 0xFFFFu); v1 = bf2f(px >> 16);
        } else {
            const float2 px = ((const float2*)x)[(size_t)row * 64 + lane];
            v0 = px.x; v1 = px.y;
        }
        const float ss = wred64(v0 * v0 + v1 * v1);
        const float nrm = sqrtf(ss);
        const float sc = nrm > 1.0f ? 1.0f / nrm : 1.0f;
        featu[(size_t)row * 64 + lane] =
            (unsigned int)f2bf(v0 * sc) | ((unsigned int)f2bf(v1 * sc) << 16);
    }
}

// D2: in-degree histogram, 4 edges/thread (4 independent atomics in flight)
__global__ __launch_bounds__(256) void hist_k(
    const int* __restrict__ ei, int* __restrict__ deg) {
    __shared__ int f_s;
    const int f_e64 = probe_e64(ei, threadIdx.x, &f_s);
    const int e0 = (blockIdx.x * 256 + threadIdx.x) * 4;
    if (e0 >= NE) return;
    int d[4];
    #pragma unroll
    for (int q = 0; q < 4; ++q) {
        const int e = e0 + q;
        d[q] = (e < NE)
            ? (f_e64 ? (int)((const long long*)ei)[NE + e] : ei[NE + e])
            : -1;
    }
    #pragma unroll
    for (int q = 0; q < 4; ++q)
        if (d[q] >= 0) atomicAdd(&deg[d[q]], 1);
}

// D3: single-dispatch exclusive scan (verified round-3 body)
__global__ __launch_bounds__(1024) void scan_k(
    const int* __restrict__ deg, int* __restrict__ offs,
    int* __restrict__ cursor, int* __restrict__ pf) {
    __shared__ int wsum[16];
    __shared__ int wbase[16];
    __shared__ int base_s;
    const int tid = threadIdx.x, lane = tid & 63, wv = tid >> 6;
    const int b = blockIdx.x;
    const int i = b * 1024 + tid;
    const int v = (i < NN) ? deg[i] : 0;
    int incl = v;
    #pragma unroll
    for (int off = 1; off < 64; off <<= 1) {
        int t = __shfl_up(incl, off, 64);
        if (lane >= off) incl += t;
    }
    if (lane == 63) wsum[wv] = incl;
    __syncthreads();
    if (wv == 0 && lane < 16) {
        const int wv_v = wsum[lane];
        int wincl = wv_v;
        #pragma unroll
        for (int off = 1; off < 16; off <<= 1) {
            int t = __shfl_up(wincl, off, 64);
            if (lane >= off) wincl += t;
        }
        wbase[lane] = wincl - wv_v;
        if (lane == 15)
            __hip_atomic_store(&pf[b], wincl + 1, __ATOMIC_RELEASE,
                               __HIP_MEMORY_SCOPE_AGENT);
    }
    if (wv == 0) {
        int val = 0;
        while (true) {
            if (lane < SCAN_BLOCKS && val == 0)
                val = __hip_atomic_load(&pf[lane], __ATOMIC_ACQUIRE,
                                        __HIP_MEMORY_SCOPE_AGENT);
            if (__ballot(lane < SCAN_BLOCKS && val == 0) == 0ull) break;
            __builtin_amdgcn_s_sleep(1);
        }
        int pv = (lane < SCAN_BLOCKS) ? val - 1 : 0;
        int ex = pv;
        #pragma unroll
        for (int off = 1; off < 64; off <<= 1) {
            int t = __shfl_up(ex, off, 64);
            if (lane >= off) ex += t;
        }
        ex -= pv;
        if (lane == b) base_s = ex;
    }
    __syncthreads();
    if (i < NN) {
        const int o = base_s + wbase[wv] + incl - v;
        offs[i] = o;
        cursor[i] = o;
    }
    if (b == 0 && tid == 0) offs[NN] = NE;
}

// D4: fill CSR adjacency, 4 edges/thread
__global__ __launch_bounds__(256) void fill_k(
    const int* __restrict__ ei, int* __restrict__ cursor,
    int* __restrict__ eidx) {
    __shared__ int f_s;
    const int f_e64 = probe_e64(ei, threadIdx.x, &f_s);
    const int e0 = (blockIdx.x * 256 + threadIdx.x) * 4;
    if (e0 >= NE) return;
    int s[4], d[4];
    #pragma unroll
    for (int q = 0; q < 4; ++q) {
        const int e = e0 + q;
        if (e < NE) {
            if (f_e64) {
                const long long* e64 = (const long long*)ei;
                s[q] = (int)e64[e]; d[q] = (int)e64[NE + e];
            } else {
                s[q] = ei[e]; d[q] = ei[NE + e];
            }
        } else d[q] = -1;
    }
    int pos[4];
    #pragma unroll
    for (int q = 0; q < 4; ++q)
        if (d[q] >= 0) pos[q] = atomicAdd(&cursor[d[q]], 1);
    #pragma unroll
    for (int q = 0; q < 4; ++q)
        if (d[q] >= 0) eidx[pos[q]] = s[q];
}

// D5/D7: aggregation — one wave per node (verified round-3 body).
// Index-in-register + shfl broadcast; lanes 0-31 gather even edges, lanes
// 32-63 odd edges (uint2 = 8B/lane, 2 neighbor rows per load instruction).
// Zero-row padding at index NN: no tail loop, no predication.
__global__ __launch_bounds__(256) void agg_k(
    const int* __restrict__ offs, const int* __restrict__ eidx,
    const uint2* __restrict__ featu2, const void* __restrict__ noise,
    const unsigned int* __restrict__ nprobe, uint2* __restrict__ aggu2) {
    __shared__ int f_s;
    const int f_nb = probe_bf16(nprobe, threadIdx.x, &f_s);
    const int node = (blockIdx.x * 256 + threadIdx.x) >> 6;
    const int lane = threadIdx.x & 63;
    if (node >= NN) return;
    const int c = lane & 31;
    const int h = lane >> 5;

    float a0, a1, a2, a3;
    if (h == 0) {
        const uint2 s = featu2[(size_t)node * 32 + c];
        a0 = bf2f(s.x & 0xFFFFu); a1 = bf2f(s.x >> 16);
        a2 = bf2f(s.y & 0xFFFFu); a3 = bf2f(s.y >> 16);
    } else {
        if (f_nb) {
            const uint2 n = ((const uint2*)noise)[(size_t)node * 32 + c];
            a0 = bf2f(n.x & 0xFFFFu); a1 = bf2f(n.x >> 16);
            a2 = bf2f(n.y & 0xFFFFu); a3 = bf2f(n.y >> 16);
        } else {
            const float4 n = ((const float4*)noise)[(size_t)node * 32 + c];
            a0 = n.x; a1 = n.y; a2 = n.z; a3 = n.w;
        }
    }
    const int e0 = offs[node];
    const int cnt = offs[node + 1] - e0;
    for (int base = 0; base < cnt; base += 64) {
        const int rem = cnt - base;
        int myi = NN;
        if (lane < rem) myi = eidx[e0 + base + lane];
        const int pairs = (rem < 64 ? rem + 1 : 64) >> 1;
        const int pb = (pairs + 7) & ~7;
        for (int p = 0; p < pb; p += 8) {
            uint2 u[8];
            #pragma unroll
            for (int q = 0; q < 8; ++q) {
                const int s = __shfl(myi, 2 * (p + q) + h, 64);
                u[q] = featu2[(size_t)s * 32 + c];
            }
            #pragma unroll
            for (int q = 0; q < 8; ++q) {
                a0 += bf2f(u[q].x & 0xFFFFu); a1 += bf2f(u[q].x >> 16);
                a2 += bf2f(u[q].y & 0xFFFFu); a3 += bf2f(u[q].y >> 16);
            }
        }
    }
    a0 += __shfl_xor(a0, 32, 64);
    a1 += __shfl_xor(a1, 32, 64);
    a2 += __shfl_xor(a2, 32, 64);
    a3 += __shfl_xor(a3, 32, 64);
    if (h == 0) {
        uint2 o;
        o.x = (unsigned int)f2bf(a0) | ((unsigned int)f2bf(a1) << 16);
        o.y = (unsigned int)f2bf(a2) | ((unsigned int)f2bf(a3) << 16);
        aggu2[(size_t)node * 32 + c] = o;
    }
}

// D6/D8: MFMA GEMM (verified round-1/3 body)
template<bool LAYER1>
__global__ __launch_bounds__(256) void gemm_k(
    const unsigned short* __restrict__ aggb,
    const unsigned short* __restrict__ Wb,
    const unsigned short* __restrict__ bb,
    unsigned short* __restrict__ featb,
    float* __restrict__ outf) {
    __shared__ unsigned short Wl[128 * 136];   // +8 pad: kills quad bank conflict
    __shared__ unsigned short bl[128];
    const int t = threadIdx.x;
    #pragma unroll
    for (int i = 0; i < 8; ++i) {
        const int idx8 = t + i * 256;
        const int base = idx8 * 8;
        const int row = base >> 7, col = base & 127;
        *(uint4*)&Wl[row * 136 + col] = ((const uint4*)Wb)[idx8];
    }
    if (t < 128) bl[t] = bb[t];

    const int lane = t & 63;
    const int w = t >> 6;
    const int n15 = lane & 15;
    const int quad = lane >> 4;
    const int rbase = blockIdx.x * 64 + w * 16;

    bf16x8 af[4];
    #pragma unroll
    for (int kc = 0; kc < 4; ++kc)
        af[kc] = *(const bf16x8*)&aggb[(size_t)(rbase + n15) * DD + kc * 32 + quad * 8];

    __syncthreads();

    float h[32];
    #pragma unroll
    for (int nt = 0; nt < 8; ++nt) {
        f32x4 acc = {0.f, 0.f, 0.f, 0.f};
        #pragma unroll
        for (int kc = 0; kc < 4; ++kc) {
            const bf16x8 bfr =
                *(const bf16x8*)&Wl[(nt * 16 + n15) * 136 + kc * 32 + quad * 8];
            acc = __builtin_amdgcn_mfma_f32_16x16x32_bf16(af[kc], bfr, acc, 0, 0, 0);
        }
        const float bj = bf2f((unsigned int)bl[nt * 16 + n15]);
        #pragma unroll
        for (int r = 0; r < 4; ++r) h[nt * 4 + r] = acc[r] + bj;
    }

    if (LAYER1) {
        const float S = 1.0507009873554805f, AL = 1.6732632423543772f;
        float ss[4] = {0.f, 0.f, 0.f, 0.f};
        #pragma unroll
        for (int nt = 0; nt < 8; ++nt)
            #pragma unroll
            for (int r = 0; r < 4; ++r) {
                float v = h[nt * 4 + r];
                v = v > 0.f ? S * v : S * AL * expm1f(v);
                h[nt * 4 + r] = v;
                ss[r] += v * v;
            }
        #pragma unroll
        for (int r = 0; r < 4; ++r) {
            #pragma unroll
            for (int off = 1; off < 16; off <<= 1)
                ss[r] += __shfl_xor(ss[r], off, 64);
        }
        #pragma unroll
        for (int r = 0; r < 4; ++r) {
            const float nr = sqrtf(ss[r]);
            const float sc = nr > 1.f ? 1.f / nr : 1.f;
            const int row = rbase + quad * 4 + r;
            if (row < NN) {
                #pragma unroll
                for (int nt = 0; nt < 8; ++nt)
                    featb[(size_t)row * DD + nt * 16 + n15] =
                        f2bf(h[nt * 4 + r] * sc);
            }
        }
    } else {
        #pragma unroll
        for (int r = 0; r < 4; ++r) {
            const int row = rbase + quad * 4 + r;
            if (row < NN) {
                #pragma unroll
                for (int nt = 0; nt < 8; ++nt)
                    outf[(size_t)row * DD + nt * 16 + n15] = h[nt * 4 + r];
            }
        }
    }
}

extern "C" void kernel_launch(void* const* d_in, const int* in_sizes, int n_in,
                              void* d_out, int out_size, void* d_ws, size_t ws_size,
                              hipStream_t stream) {
    const void* x  = d_in[0];
    const int*  ei = (const int*)d_in[1];
    const void* W1 = d_in[2];
    const void* b1 = d_in[3];
    const void* W2 = d_in[4];
    const void* b2 = d_in[5];
    const void* n1 = d_in[6];
    const void* n2 = d_in[7];

    // ws layout (~16 MB)
    unsigned short* aggb = (unsigned short*)d_ws;        // NPAD*128 bf16
    unsigned short* W1b  = aggb + (size_t)NPAD * DD;
    unsigned short* b1b  = W1b + DD * DD;
    unsigned short* W2b  = b1b + DD;
    unsigned short* b2b  = W2b + DD * DD;
    int* deg    = (int*)(b2b + DD);
    int* offs   = deg + NN;
    int* cursor = offs + NN + 1;
    int* pf     = cursor + NN;
    int* eidx   = pf + 64;
    unsigned int* featu = (unsigned int*)d_out;          // features (NN+1 rows)

    // D1: probe + convert + zero + prep
    setup_k<<<SETUP_BLOCKS, 256, 0, stream>>>(
        x, W1, b1, W2, b2, W1b, b1b, W2b, b2b, deg, pf, featu);
    // D2-D4: CSR build
    hist_k<<<E4_BLOCKS, 256, 0, stream>>>(ei, deg);
    scan_k<<<SCAN_BLOCKS, 1024, 0, stream>>>(deg, offs, cursor, pf);
    fill_k<<<E4_BLOCKS, 256, 0, stream>>>(ei, cursor, eidx);
    // D5-D6: layer 1
    agg_k<<<(NN * 64) / 256, 256, 0, stream>>>(offs, eidx, (const uint2*)featu,
                                               n1, (const unsigned int*)n1,
                                               (uint2*)aggb);
    gemm_k<true><<<NTILE, 256, 0, stream>>>(aggb, W1b, b1b,
                                            (unsigned short*)featu, nullptr);
    // D7-D8: layer 2 (featu/d_out holds hc bf16; row NN still zero)
    agg_k<<<(NN * 64) / 256, 256, 0, stream>>>(offs, eidx, (const uint2*)featu,
                                               n2, (const unsigned int*)n1,
                                               (uint2*)aggb);
    gemm_k<false><<<NTILE, 256, 0, stream>>>(aggb, W2b, b2b, nullptr,
                                             (float*)d_out);
}